// Round 13
// baseline (387.010 us; speedup 1.0000x reference)
//
#include <hip/hip_runtime.h>
#include <hip/hip_bf16.h>

// QLayerQuantum: out[b][h] = sum_k cumprod(cos(x[b]))[k] * W[h][k] + bias[h]
// B=65536, NQ=32, H=1024.
//
// r11: LDS-free 2-kernel version = 302.3us total (r5 fused = 335.5).
// dur_us includes harness re-poison fills (~210us: 1GiB ws + 256MB out),
// so gemm kernel itself is bounded [0,92]us vs 46us write floor.
// This round: (a) double-buffered z-row prefetch pipeline (hide z-load
// latency, the suspected limiter: z rows come from another block's XCD ->
// L2 miss -> ~900cyc HBM latency vs ~400cyc of TLP cover), and
// (b) launch gemm TWICE (idempotent) so r12/r13 dur difference measures
// Kg exactly: dur_r12 = O + Kz + 2*Kg, dur_r13 = O + Kz + Kg.

#define B_TOT 65536
#define NQ    32
#define H_TOT 1024
#define ROWS_PER_BLK 64
#define COLS_PER_BLK 512   // 256 threads * 2 cols

typedef float v2f __attribute__((ext_vector_type(2)));

__global__ __launch_bounds__(256) void zscan_kernel(
    const float* __restrict__ x,   // [B][NQ]
    float* __restrict__ z)         // [B][NQ] out
{
    const int g = threadIdx.x >> 5;      // 8 row-groups per block
    const int l = threadIdx.x & 31;
    const int row = blockIdx.x * 8 + g;
    float v = __cosf(x[row * NQ + l]);
#pragma unroll
    for (int d = 1; d < 32; d <<= 1) {   // inclusive product scan over 32 lanes
        float o = __shfl_up(v, d, 32);
        if (l >= d) v *= o;
    }
    z[row * NQ + l] = v;
}

__global__ __launch_bounds__(256) void gemm_kernel(
    const float* __restrict__ z,    // [B][NQ]
    const float* __restrict__ W,    // [H][NQ]
    const float* __restrict__ bias, // [H]
    float* __restrict__ out)        // [B][H]
{
    const int tid = threadIdx.x;
    const int r0  = blockIdx.x * ROWS_PER_BLK;
    const int c0  = blockIdx.y * COLS_PER_BLK + tid * 2;

    // ---- W columns c0, c0+1 into registers (one-time, 64 KB/block from L2) ----
    float w0[NQ], w1[NQ];
    const float4* wg0 = reinterpret_cast<const float4*>(W + (size_t)c0 * NQ);
    const float4* wg1 = reinterpret_cast<const float4*>(W + (size_t)(c0 + 1) * NQ);
#pragma unroll
    for (int i = 0; i < 8; ++i) {
        float4 a = wg0[i];
        w0[4*i+0] = a.x; w0[4*i+1] = a.y; w0[4*i+2] = a.z; w0[4*i+3] = a.w;
        float4 b = wg1[i];
        w1[4*i+0] = b.x; w1[4*i+1] = b.y; w1[4*i+2] = b.z; w1[4*i+3] = b.w;
    }
    const float b0 = bias[c0];
    const float b1 = bias[c0 + 1];

    const float4* zp = reinterpret_cast<const float4*>(z + (size_t)r0 * NQ);
    float* op = out + (size_t)r0 * H_TOT + c0;

    // ---- double-buffered row pipeline: zA=row r, zB=row r+1 in flight ----
    float4 zA[8], zB[8];
#pragma unroll
    for (int i = 0; i < 8; ++i) zA[i] = zp[i];        // row 0
#pragma unroll
    for (int i = 0; i < 8; ++i) zB[i] = zp[8 + i];    // row 1

#pragma unroll 1
    for (int r = 0; r < ROWS_PER_BLK; r += 2) {
        // compute row r from zA
        {
            const float* zk = reinterpret_cast<const float*>(zA);
            float a0 = b0, a1 = b1;
#pragma unroll
            for (int k = 0; k < NQ; ++k) { a0 += zk[k] * w0[k]; a1 += zk[k] * w1[k]; }
            v2f o; o.x = a0; o.y = a1;
            __builtin_nontemporal_store(o,
                reinterpret_cast<v2f*>(op + (size_t)r * H_TOT));
        }
        // prefetch row r+2 into zA (issues now, waits ~2 rows later)
        if (r + 2 < ROWS_PER_BLK) {
#pragma unroll
            for (int i = 0; i < 8; ++i) zA[i] = zp[(r + 2) * 8 + i];
        }
        // compute row r+1 from zB
        {
            const float* zk = reinterpret_cast<const float*>(zB);
            float a0 = b0, a1 = b1;
#pragma unroll
            for (int k = 0; k < NQ; ++k) { a0 += zk[k] * w0[k]; a1 += zk[k] * w1[k]; }
            v2f o; o.x = a0; o.y = a1;
            __builtin_nontemporal_store(o,
                reinterpret_cast<v2f*>(op + (size_t)(r + 1) * H_TOT));
        }
        // prefetch row r+3 into zB
        if (r + 3 < ROWS_PER_BLK) {
#pragma unroll
            for (int i = 0; i < 8; ++i) zB[i] = zp[(r + 3) * 8 + i];
        }
    }
}

extern "C" void kernel_launch(void* const* d_in, const int* in_sizes, int n_in,
                              void* d_out, int out_size, void* d_ws, size_t ws_size,
                              hipStream_t stream) {
    const float* x = (const float*)d_in[0];
    const float* W = (const float*)d_in[1];
    const float* b = (const float*)d_in[2];
    float* out = (float*)d_out;
    float* z   = (float*)d_ws;           // 8 MB of the 1 GiB workspace

    zscan_kernel<<<dim3(B_TOT / 8), dim3(256), 0, stream>>>(x, z);
    // Launched TWICE on purpose (idempotent): r12 vs r13 dur difference
    // measures the gemm kernel's exact duration through the fill-floor.
    gemm_kernel<<<dim3(B_TOT / ROWS_PER_BLK, H_TOT / COLS_PER_BLK),
                  dim3(256), 0, stream>>>(z, W, b, out);
    gemm_kernel<<<dim3(B_TOT / ROWS_PER_BLK, H_TOT / COLS_PER_BLK),
                  dim3(256), 0, stream>>>(z, W, b, out);
}